// Round 23
// baseline (2351.977 us; speedup 1.0000x reference)
//
#include <hip/hip_runtime.h>
#include <hip/hip_bf16.h>

#define TT 2048
#define DD 768
#define HH 6
#define HDIM 128
#define NL 12
#define NBL 16
#define BLKSZ 128
#define DFF 3072
#define VP 50304
#define NV 50257
#define EPSF 1.1920929e-07f

typedef unsigned short u16;
typedef __attribute__((ext_vector_type(8))) short short8v;
typedef __attribute__((ext_vector_type(4))) float f32x4;
typedef __attribute__((address_space(3))) void lds_void;
typedef __attribute__((address_space(1))) void gbl_void;

__device__ __forceinline__ u16 f2bf(float f){
  unsigned u = __float_as_uint(f);
  return (u16)((u + 0x7fffu + ((u >> 16) & 1u)) >> 16);
}
__device__ __forceinline__ float bf2f(u16 u){
  return __uint_as_float((unsigned)u << 16);
}
__device__ __forceinline__ void async16(const void* g, void* l){
  __builtin_amdgcn_global_load_lds((const gbl_void*)g, (lds_void*)l, 16, 0, 0);
}

// ---------- reduction helpers ----------
__device__ __forceinline__ float wave_sum(float v){
#pragma unroll
  for (int o = 32; o > 0; o >>= 1) v += __shfl_xor(v, o);
  return v;
}
__device__ __forceinline__ float block_sum(float v){
  __shared__ float sh[9];
  int lane = threadIdx.x & 63, w = threadIdx.x >> 6;
  v = wave_sum(v);
  if (lane == 0) sh[w] = v;
  __syncthreads();
  if (threadIdx.x == 0){
    float tot = 0.f;
    int nw = (blockDim.x + 63) >> 6;
    for (int i = 0; i < nw; i++) tot += sh[i];
    sh[8] = tot;
  }
  __syncthreads();
  return sh[8];
}

// ---------- fp32 -> bf16 bulk convert, all 5 weight tensors in one launch ----------
__global__ void k_f2bf_all(const float* __restrict__ qkvw, const float* __restrict__ aproj,
                           const float* __restrict__ fcw, const float* __restrict__ mproj,
                           const float* __restrict__ lmw,
                           u16* __restrict__ qkvw_bf, u16* __restrict__ aprojw_bf,
                           u16* __restrict__ fcw_bf, u16* __restrict__ mprojw_bf,
                           u16* __restrict__ lmw_bf){
  const long S0 = 2654208;            // qkv groups (12*2304*768/8)
  const long S1 = S0 + 884736;        // + aproj
  const long S2 = S1 + 3538944;       // + fc
  const long S3 = S2 + 3538944;       // + mproj
  const long S4 = S3 + 4829184;       // + lm_head
  long stride = (long)gridDim.x * blockDim.x;
  for (long g = (long)blockIdx.x * blockDim.x + threadIdx.x; g < S4; g += stride){
    const float* in; u16* out; long off;
    if (g < S0){ in = qkvw;  out = qkvw_bf;  off = g; }
    else if (g < S1){ in = aproj; out = aprojw_bf; off = g - S0; }
    else if (g < S2){ in = fcw;   out = fcw_bf;   off = g - S1; }
    else if (g < S3){ in = mproj; out = mprojw_bf; off = g - S2; }
    else { in = lmw; out = lmw_bf; off = g - S3; }
    const float4* p = (const float4*)(in + off * 8);
    float4 a = p[0], b = p[1];
    u16 o[8] = { f2bf(a.x), f2bf(a.y), f2bf(a.z), f2bf(a.w),
                 f2bf(b.x), f2bf(b.y), f2bf(b.z), f2bf(b.w) };
    *(ulonglong2*)(out + off * 8) = *(const ulonglong2*)o;
  }
}

// ---------- docs + block masks (wave-parallel cumsum) ----------
__global__ void k_docs_masks(const int* __restrict__ seq, const int* __restrict__ swnb,
                             int* __restrict__ docs, int* __restrict__ bmask){
  int lane = threadIdx.x;   // 64 threads
  int cnt = 0;
  for (int i = 0; i < 32; i++) cnt += (seq[lane*32 + i] == 50256);
  int incl = cnt;
#pragma unroll
  for (int o = 1; o < 64; o <<= 1){
    int v = __shfl_up(incl, o);
    if (lane >= o) incl += v;
  }
  int run = incl - cnt;
  for (int i = 0; i < 32; i++){
    int t = lane*32 + i;
    run += (seq[t] == 50256);
    docs[t] = run;
  }
  __syncthreads();
  if (lane != 0) return;
  int dlo[NBL], dhi[NBL];
  for (int b = 0; b < NBL; b++){ dlo[b] = docs[b*BLKSZ]; dhi[b] = docs[b*BLKSZ + BLKSZ-1]; }
  int allb[NBL][NBL], partb[NBL][NBL];
  for (int i = 0; i < NBL; i++)
    for (int j = 0; j < NBL; j++){
      int a = (i >= j) && (dlo[i] <= dhi[j]) && (dhi[i] >= dlo[j]);
      int f = (i >  j) && (dlo[i] == dhi[j]) && (dhi[i] == dlo[j]);
      allb[i][j] = f; partb[i][j] = a && !f;
    }
  int sws[2]; sws[0] = swnb[0]; sws[1] = swnb[0] / 2;
  for (int m = 0; m < 2; m++){
    int sw = sws[m];
    for (int i = 0; i < NBL; i++){
      int fullcnt = 0;
      for (int j = 0; j < NBL; j++) fullcnt += allb[i][j];
      int pth = sw - fullcnt; if (pth < 1) pth = 1;
      int pr = 0, fr = 0;
      for (int j = NBL-1; j >= 0; j--){
        int kp = partb[i][j] && (pr < pth);
        int kf = allb[i][j]  && (fr < sw - 1);
        bmask[(m*2+0)*NBL*NBL + i*NBL + j] = kf;
        bmask[(m*2+1)*NBL*NBL + i*NBL + j] = kp;
        pr += partb[i][j]; fr += allb[i][j];
      }
    }
  }
}

// ---------- embedding gather + rmsnorm + ve gathers + rotary tables ----------
__global__ void k_embed(const int* __restrict__ seq, const float* __restrict__ embw,
                        const float* __restrict__ vew, float* __restrict__ x,
                        float* __restrict__ x0, u16* __restrict__ veg,
                        float* __restrict__ cosb, float* __restrict__ sinb){
  int t = blockIdx.x;
  if (threadIdx.x < 64){
    int j = threadIdx.x;
    float c = 1.f, s = 0.f;
    if (j < 32){
      float af = powf(1.0f/1024.0f, (float)j / 31.0f);
      float th = (float)t * af;
      c = cosf(th); s = sinf(th);
    }
    cosb[t*64 + j] = c; sinb[t*64 + j] = s;
  }
  int tok = seq[t];
  const float* row = embw + (size_t)tok * DD;
  float ss = 0.f;
  for (int d = threadIdx.x; d < DD; d += blockDim.x){ float v = row[d]; ss += v*v; }
  float tot = block_sum(ss);
  float rn = rsqrtf(tot / DD + EPSF);
  for (int d = threadIdx.x; d < DD; d += blockDim.x){
    float v = row[d] * rn;
    x[(size_t)t*DD + d] = v; x0[(size_t)t*DD + d] = v;
  }
  for (int j = 0; j < 3; j++){
    const float* vr = vew + ((size_t)j*NV + tok) * DD;
    u16* dst = veg + ((size_t)j*TT + t) * DD;
    for (int d = threadIdx.x; d < DD; d += blockDim.x) dst[d] = f2bf(vr[d]);
  }
}

// ---------- row rmsnorm -> bf16 (optional rowsum zeroing for loss) ----------
__global__ void k_rmsnorm_bf(const float* __restrict__ in, u16* __restrict__ out,
                             float* __restrict__ rowsum){
  int t = blockIdx.x;
  if (rowsum && threadIdx.x == 0) rowsum[t] = 0.f;
  const float* r = in + (size_t)t * DD;
  float ss = 0.f;
  for (int d = threadIdx.x; d < DD; d += blockDim.x){ float v = r[d]; ss += v*v; }
  float tot = block_sum(ss);
  float rn = rsqrtf(tot / DD + EPSF);
  u16* o = out + (size_t)t * DD;
  for (int d = threadIdx.x; d < DD; d += blockDim.x) o[d] = f2bf(r[d] * rn);
}

// ---------- fused: [save incoming x to sk_out]; x = bl0*(x [+ sw*sk]) + bl1*x0; xn = bf16(rmsnorm(x)) ----------
__global__ void k_premix_norm(float* __restrict__ x, const float* __restrict__ x0,
                              const float* __restrict__ sk, float* __restrict__ sk_out,
                              const float* __restrict__ skw, int j,
                              const float* __restrict__ bl, int layer, u16* __restrict__ xn){
  int t = blockIdx.x;
  float bl0 = bl[layer*2], bl1 = bl[layer*2 + 1];
  float sw = sk ? skw[j] : 0.f;
  float vloc[3];
  float ss = 0.f;
  int base = t * DD;
#pragma unroll
  for (int k = 0; k < 3; k++){
    int d = threadIdx.x + k*256;
    float xin = x[base + d];
    if (sk_out) sk_out[base + d] = xin;
    float v = xin;
    if (sk) v += sw * sk[base + d];
    v = bl0 * v + bl1 * x0[base + d];
    vloc[k] = v; ss += v*v;
  }
  float tot = block_sum(ss);
  float rn = rsqrtf(tot / DD + EPSF);
#pragma unroll
  for (int k = 0; k < 3; k++){
    int d = threadIdx.x + k*256;
    x[base + d] = vloc[k];
    xn[base + d] = f2bf(vloc[k] * rn);
  }
}

// ---------- MFMA bf16 GEMM 128xBN tile, XCD-chunked + LDS XOR-swizzle ----------
// MODE 3: Cbf = bf16(relu(acc)^2)
// MODE 4 (BN=128): qkv fused: q/k tiles -> rmsnorm+rope -> bf16 qbf/kbf; v tiles -> vtb
// MODE 5: split-K: C += partial via atomicAdd; blockIdx.y = K-slice, K=slice len, ldk=row stride
// BN=64 uses double-buffered LDS + counted vmcnt prefetch (T3-min schedule).
template<int MODE, int BN>
__global__ __launch_bounds__(256, (BN == 64) ? 3 : 2)
void k_mfma_gemm(const u16* __restrict__ A, const u16* __restrict__ B,
                 float* __restrict__ C, u16* __restrict__ Cbf,
                 const u16* __restrict__ vegp, const float* __restrict__ lam,
                 int layer, u16* __restrict__ vtb,
                 const float* __restrict__ cosb, const float* __restrict__ sinb,
                 u16* __restrict__ qbf, u16* __restrict__ kbf,
                 int N, int K, int ldk, int nbn){
  constexpr int NW   = BN / 32;          // acc cols per wave (2 or 4)
  constexpr int BC   = BN / 32;          // B chunks per wave (2 or 4)
  constexpr int NBUF = (BN == 64) ? 2 : 1;
  __shared__ u16 As[NBUF][128*64];
  __shared__ u16 Bs[NBUF][BN*64];
  __shared__ float qt[(MODE == 4) ? 32*132 : 1];   // q/k epilogue stage (16.9 KB)
  int per = (nbn << 4) >> 3;                 // nwg/8 (requires 16*nbn % 8 == 0)
  int x = (blockIdx.x & 7) * per + (blockIdx.x >> 3);
  int bm = (x & 15) << 7;
  int bn = (x >> 4) * BN;
  int koff = (MODE == 5) ? blockIdx.y * K : 0;
  int tid = threadIdx.x;
  int wid = tid >> 6, lane = tid & 63;
  int wr = wid >> 1, wc = wid & 1;
  int srow = lane >> 3;                      // 0..7 within chunk (== row&7)
  int scol = (((lane & 7) ^ srow) * 8);      // pre-swizzled global col slot
  int l15 = lane & 15, l16 = lane >> 4;
  // precompute staging pointers; bump by 64 elements per stage
  const u16* pa[4];
  const u16* pb[BC];
#pragma unroll
  for (int c = 0; c < 4; c++){
    int row = (wid*4 + c)*8 + srow;
    pa[c] = A + (size_t)(bm + row) * ldk + koff + scol;
  }
#pragma unroll
  for (int c = 0; c < BC; c++){
    int row = (wid*BC + c)*8 + srow;
    pb[c] = B + (size_t)(bn + row) * ldk + koff + scol;
  }
  f32x4 acc[4][NW] = {};
  auto stage = [&](int buf){
#pragma unroll
    for (int c = 0; c < 4; c++){
      async16(pa[c], &As[buf][(wid*4 + c) * 512]);
      pa[c] += 64;
    }
#pragma unroll
    for (int c = 0; c < BC; c++){
      async16(pb[c], &Bs[buf][(wid*BC + c) * 512]);
      pb[c] += 64;
    }
  };
  auto compute = [&](int buf){
#pragma unroll
    for (int kk = 0; kk < 2; kk++){
      short8v a[4], b[NW];
#pragma unroll
      for (int m = 0; m < 4; m++){
        int row = wr*64 + m*16 + l15;
        a[m] = *(const short8v*)(&As[buf][row*64 + ((((kk<<2)|l16) ^ (row&7))<<3)]);
      }
#pragma unroll
      for (int n = 0; n < NW; n++){
        int row = wc*(BN/2) + n*16 + l15;
        b[n] = *(const short8v*)(&Bs[buf][row*64 + ((((kk<<2)|l16) ^ (row&7))<<3)]);
      }
#pragma unroll
      for (int m = 0; m < 4; m++)
#pragma unroll
        for (int n = 0; n < NW; n++)
          acc[m][n] = __builtin_amdgcn_mfma_f32_16x16x32_bf16(a[m], b[n], acc[m][n], 0, 0, 0);
    }
  };
  if constexpr (BN == 64){
    // double-buffered, counted-vmcnt prefetch
    stage(0);
    int KT = K >> 6;
    for (int t = 0; t < KT; t++){
      int cur = t & 1;
      if (t + 1 < KT){
        stage(cur ^ 1);
        asm volatile("s_waitcnt vmcnt(6)" ::: "memory");
      } else {
        asm volatile("s_waitcnt vmcnt(0)" ::: "memory");
      }
      __builtin_amdgcn_s_barrier();
      asm volatile("" ::: "memory");
      compute(cur);
      asm volatile("" ::: "memory");
      __builtin_amdgcn_s_barrier();
    }
  } else {
    for (int k0 = 0; k0 < K; k0 += 64){
      stage(0);
      __syncthreads();
      compute(0);
      __syncthreads();
    }
  }
  if (MODE == 4){
    if (bn >= 1536){
      // v tile: head h = (bn-1536)/128; mix with ve, write transposed vtb[h][d][t]
      int h = (bn - 1536) >> 7;
      float l0 = lam[layer*2], l1 = lam[layer*2 + 1];
#pragma unroll
      for (int m = 0; m < 4; m++){
        int t0 = bm + wr*64 + m*16 + l16*4;
#pragma unroll
        for (int n = 0; n < NW; n++){
          int d = wc*64 + n*16 + l15;
          u16 o[4];
#pragma unroll
          for (int j = 0; j < 4; j++){
            float v = l0 * acc[m][n][j];
            if (vegp) v += l1 * bf2f(vegp[(size_t)(t0 + j)*DD + h*HDIM + d]);
            o[j] = f2bf(v);
          }
          *(ushort4*)(vtb + ((size_t)(h*HDIM + d))*TT + t0) = *(const ushort4*)o;
        }
      }
    } else {
      // q/k tile: 4 passes of 32 rows through LDS, rmsnorm + rope -> bf16
      int h = (bn < 768) ? (bn >> 7) : ((bn - 768) >> 7);
      u16* dstb = (bn < 768) ? qbf : kbf;
#pragma unroll
      for (int p = 0; p < 4; p++){
        if (wr == (p >> 1)){
#pragma unroll
          for (int mm = 0; mm < 2; mm++){
            int m = (p & 1)*2 + mm;
#pragma unroll
            for (int n = 0; n < NW; n++){
              int col = wc*64 + n*16 + l15;
#pragma unroll
              for (int j = 0; j < 4; j++){
                int lr = m*16 + l16*4 + j - (p & 1)*32;
                qt[lr*132 + col] = acc[m][n][j];
              }
            }
          }
        }
        __syncthreads();
        {
          int row = tid >> 3, part = tid & 7;   // 8 threads/row, 16 dims each
          int tok = bm + p*32 + row;
          float ss = 0.f;
#pragma unroll
          for (int jj = 0; jj < 16; jj++){
            float v = qt[row*132 + part*16 + jj];
            ss += v*v;
          }
          ss += __shfl_xor(ss, 1); ss += __shfl_xor(ss, 2); ss += __shfl_xor(ss, 4);
          float rn = rsqrtf(ss / 128.f + EPSF);
          if (part < 4){
            u16* dst = dstb + ((size_t)(h*TT + tok))*HDIM;
#pragma unroll
            for (int jj = 0; jj < 16; jj++){
              int j = part*16 + jj;
              float c = cosb[tok*64 + j], s = sinb[tok*64 + j];
              float v1 = qt[row*132 + j] * rn;
              float v2 = qt[row*132 + j + 64] * rn;
              dst[j]      = f2bf(v1*c + v2*s);
              dst[j + 64] = f2bf(-v1*s + v2*c);
            }
          }
        }
        __syncthreads();
      }
    }
    return;
  }
#pragma unroll
  for (int m = 0; m < 4; m++){
    int row = bm + wr*64 + m*16 + l16*4;
#pragma unroll
    for (int j = 0; j < 4; j++){
      if (MODE == 3){
        u16* cb = Cbf + (size_t)(row + j) * N + bn + wc*(BN/2) + l15;
#pragma unroll
        for (int n = 0; n < NW; n++){
          float v = fmaxf(acc[m][n][j], 0.f);
          cb[n*16] = f2bf(v * v);
        }
      } else if (MODE == 5){
        float* cp = C + (size_t)(row + j) * N + bn + wc*(BN/2) + l15;
#pragma unroll
        for (int n = 0; n < NW; n++) atomicAdd(cp + n*16, acc[m][n][j]);
      } else {
        float* cp = C + (size_t)(row + j) * N + bn + wc*(BN/2) + l15;
#pragma unroll
        for (int n = 0; n < NW; n++) cp[n*16] = acc[m][n][j];
      }
    }
  }
}

// ---------- lm_head loss GEMM: 128x128 tile, 512 threads (2x4 waves), dbuf + counted vmcnt ----------
__global__ __launch_bounds__(512) void k_loss_mfma(const u16* __restrict__ A, const u16* __restrict__ B,
                                                   const int* __restrict__ tgt, float* __restrict__ rowsum,
                                                   float* __restrict__ tl){
  __shared__ u16 As[2][128*64];
  __shared__ u16 Bs[2][128*64];
  const int nbn = VP/128;                    // 393
  int per = (nbn << 4) >> 3;
  int x = (blockIdx.x & 7) * per + (blockIdx.x >> 3);
  int bm = (x & 15) << 7;
  int bn = (x >> 4) << 7;
  int tid = threadIdx.x;
  int wid = tid >> 6, lane = tid & 63;
  int wr = wid >> 2, wn = wid & 3;           // 2 x 4 wave grid; wave tile 64x32
  int srow = lane >> 3;
  int scol = (((lane & 7) ^ srow) * 8);
  int l15 = lane & 15, l16 = lane >> 4;
  const u16* pa[2];
  const u16* pb[2];
#pragma unroll
  for (int c = 0; c < 2; c++){
    int row = (wid*2 + c)*8 + srow;
    pa[c] = A + (size_t)(bm + row) * DD + scol;
    pb[c] = B + (size_t)(bn + row) * DD + scol;
  }
  f32x4 acc[4][2] = {};
  auto stage = [&](int buf){
#pragma unroll
    for (int c = 0; c < 2; c++){
      async16(pa[c], &As[buf][(wid*2 + c) * 512]);
      async16(pb[c], &Bs[buf][(wid*2 + c) * 512]);
      pa[c] += 64; pb[c] += 64;
    }
  };
  auto compute = [&](int buf){
#pragma unroll
    for (int kk = 0; kk < 2; kk++){
      short8v a[4], b[2];
#pragma unroll
      for (int m = 0; m < 4; m++){
        int row = wr*64 + m*16 + l15;
        a[m] = *(const short8v*)(&As[buf][row*64 + ((((kk<<2)|l16) ^ (row&7))<<3)]);
      }
#pragma unroll
      for (int n = 0; n < 2; n++){
        int row = wn*32 + n*16 + l15;
        b[n] = *(const short8v*)(&Bs[buf][row*64 + ((((kk<<2)|l16) ^ (row&7))<<3)]);
      }
#pragma unroll
      for (int m = 0; m < 4; m++)
#pragma unroll
        for (int n = 0; n < 2; n++)
          acc[m][n] = __builtin_amdgcn_mfma_f32_16x16x32_bf16(a[m], b[n], acc[m][n], 0, 0, 0);
    }
  };
  stage(0);
  const int KT = DD >> 6;                    // 12
  for (int t = 0; t < KT; t++){
    int cur = t & 1;
    if (t + 1 < KT){
      stage(cur ^ 1);
      asm volatile("s_waitcnt vmcnt(4)" ::: "memory");
    } else {
      asm volatile("s_waitcnt vmcnt(0)" ::: "memory");
    }
    __builtin_amdgcn_s_barrier();
    asm volatile("" ::: "memory");
    __builtin_amdgcn_s_setprio(1);
    compute(cur);
    __builtin_amdgcn_s_setprio(0);
    asm volatile("" ::: "memory");
    __builtin_amdgcn_s_barrier();
  }
  const float INVS = 0.0048112522432469f; // 1/(7.5*sqrt(768))
#pragma unroll
  for (int m = 0; m < 4; m++){
#pragma unroll
    for (int j = 0; j < 4; j++){
      int row = bm + wr*64 + m*16 + l16*4 + j;
      int tg = tgt[row];
      float rs = 0.f;
#pragma unroll
      for (int n = 0; n < 2; n++){
        int col = bn + wn*32 + n*16 + l15;
        float lg = 30.f * __builtin_amdgcn_rcpf(1.f + __expf(-acc[m][n][j] * INVS));
        rs += __expf(lg);
        if (col == tg) tl[row] = lg;
      }
      rs += __shfl_xor(rs, 1); rs += __shfl_xor(rs, 2);
      rs += __shfl_xor(rs, 4); rs += __shfl_xor(rs, 8);
      if (l15 == 0) atomicAdd(&rowsum[row], rs);
    }
  }
}

// ---------- MFMA flash attention: QBLK=32, 128 threads (2 waves), 384 blocks ----------
__global__ __launch_bounds__(128) void k_attn_mfma(
    const u16* __restrict__ qbf, const u16* __restrict__ kbf, const u16* __restrict__ vtb,
    u16* __restrict__ y, const int* __restrict__ docs,
    const int* __restrict__ kfm, const int* __restrict__ kpm){
  __shared__ u16 Ks[128*128];   // K block; rows 0..31 reused for P
  __shared__ u16 Vs[128*128];   // V^T block [d][k]
  __shared__ int docsL[128];
  __shared__ int kb[NBL], kfl[NBL];
  __shared__ int nkb_sh;
  // 384 blocks = 8 XCD chunks x 48; head-major within chunk, longest qtile first
  int wg = (blockIdx.x & 7) * 48 + (blockIdx.x >> 3);
  int h = wg >> 6;
  int qb = (63 - (wg & 63)) * 32;
  int bt = qb >> 7;
  int tid = threadIdx.x;
  int w = tid >> 6, lane = tid & 63;
  int l15 = lane & 15, l16 = lane >> 4;
  if (tid == 0){
    int n = 0;
    for (int sb = 0; sb <= bt; sb++){
      int kf = kfm[bt*NBL + sb], kp = kpm[bt*NBL + sb];
      if (kf || kp){ kb[n] = sb; kfl[n] = kf; n++; }
    }
    nkb_sh = n;
  }
  short8v q[4];
  {
    const u16* qrow = qbf + ((size_t)(h*TT + qb + w*16 + l15))*HDIM;
#pragma unroll
    for (int kc = 0; kc < 4; kc++) q[kc] = *(const short8v*)(qrow + kc*32 + l16*8);
  }
  int t_row[4], dq[4];
#pragma unroll
  for (int j = 0; j < 4; j++){
    t_row[j] = qb + w*16 + l16*4 + j;
    dq[j] = docs[t_row[j]];
  }
  f32x4 o[8] = {};
  float m[4], l[4];
#pragma unroll
  for (int j = 0; j < 4; j++){ m[j] = -1e30f; l[j] = 0.f; }
  __syncthreads();
  int nkb = nkb_sh;
  for (int bi = 0; bi < nkb; bi++){
    int kbi = kb[bi], kf = kfl[bi];
    __syncthreads();                      // prev-iter readers done
    {
      const u16* ksrc = kbf + ((size_t)(h*TT + kbi*128))*HDIM;
      const u16* vsrc = vtb + ((size_t)(h*HDIM))*TT + kbi*128;
#pragma unroll
      for (int p = 0; p < 16; p++){
        int idx = tid + p*128;
        int r = idx >> 4, c = (idx & 15) * 8;
        short8v kv = *(const short8v*)(ksrc + (size_t)r*HDIM + c);
        *(short8v*)(Ks + ((r*128 + c) ^ ((r&7)<<3))) = kv;
        short8v vv = *(const short8v*)(vsrc + (size_t)r*TT + c);
        *(short8v*)(Vs + ((r*128 + c) ^ ((r&7)<<3))) = vv;
      }
      if (tid < 32) ((int4*)docsL)[tid] = ((const int4*)(docs + kbi*128))[tid];
    }
    __syncthreads();
    // S = Q K^T
    f32x4 s[8];
#pragma unroll
    for (int n = 0; n < 8; n++){
      f32x4 acc = {};
#pragma unroll
      for (int kc = 0; kc < 4; kc++){
        int row = n*16 + l15;
        short8v b = *(const short8v*)(Ks + ((row*128 + kc*32 + l16*8) ^ ((row&7)<<3)));
        acc = __builtin_amdgcn_mfma_f32_16x16x32_bf16(q[kc], b, acc, 0, 0, 0);
      }
      s[n] = acc;
    }
    int sbase = kbi*128;
    float bmax[4];
#pragma unroll
    for (int j = 0; j < 4; j++) bmax[j] = -1e30f;
#pragma unroll
    for (int n = 0; n < 8; n++){
      int sg = sbase + n*16 + l15;
      int ds = docsL[n*16 + l15];
#pragma unroll
      for (int j = 0; j < 4; j++){
        float sv = s[n][j] * 0.12f;
        bool keep = kf || ((sg <= t_row[j]) && (ds == dq[j]));
        sv = keep ? sv : -1e30f;
        s[n][j] = sv;
        bmax[j] = fmaxf(bmax[j], sv);
      }
    }
#pragma unroll
    for (int j = 0; j < 4; j++){
#pragma unroll
      for (int off = 1; off < 16; off <<= 1) bmax[j] = fmaxf(bmax[j], __shfl_xor(bmax[j], off));
      float nm = fmaxf(m[j], bmax[j]);
      float r = __expf(m[j] - nm);
      m[j] = nm; l[j] *= r;
#pragma unroll
      for (int n = 0; n < 8; n++) o[n][j] *= r;
    }
    __syncthreads();                      // all waves done reading Ks
#pragma unroll
    for (int n = 0; n < 8; n++){
#pragma unroll
      for (int j = 0; j < 4; j++){
        float sv = s[n][j];
        float p = (sv > -1e29f) ? __expf(sv - m[j]) : 0.f;
        l[j] += p;
        int prow = w*16 + l16*4 + j;
        Ks[((prow*128) + n*16 + l15) ^ ((prow&7)<<3)] = f2bf(p);
      }
    }
    __syncthreads();
    short8v a[4];
    {
      int prow = w*16 + l15;
#pragma unroll
      for (int kc = 0; kc < 4; kc++)
        a[kc] = *(const short8v*)(Ks + ((prow*128 + kc*32 + l16*8) ^ ((prow&7)<<3)));
    }
#pragma unroll
    for (int n = 0; n < 8; n++){
#pragma unroll
      for (int kc = 0; kc < 4; kc++){
        int vrow = n*16 + l15;
        short8v b = *(const short8v*)(Vs + ((vrow*128 + kc*32 + l16*8) ^ ((vrow&7)<<3)));
        o[n] = __builtin_amdgcn_mfma_f32_16x16x32_bf16(a[kc], b, o[n], 0, 0, 0);
      }
    }
  }
  float inv[4];
#pragma unroll
  for (int j = 0; j < 4; j++){
    float lt = l[j];
#pragma unroll
    for (int off = 1; off < 16; off <<= 1) lt += __shfl_xor(lt, off);
    inv[j] = 1.f / lt;
  }
#pragma unroll
  for (int n = 0; n < 8; n++){
#pragma unroll
    for (int j = 0; j < 4; j++)
      y[(size_t)t_row[j]*DD + h*HDIM + n*16 + l15] = f2bf(o[n][j] * inv[j]);
  }
}

__global__ void k_loss_final(const float* __restrict__ rowsum, const float* __restrict__ tl,
                             float* __restrict__ out){
  float a = 0.f;
  for (int t = threadIdx.x; t < TT; t += 256) a += logf(rowsum[t]) - tl[t];
  a = block_sum(a);
  if (threadIdx.x == 0) out[0] = a / TT;
}

extern "C" void kernel_launch(void* const* d_in, const int* in_sizes, int n_in,
                              void* d_out, int out_size, void* d_ws, size_t ws_size,
                              hipStream_t stream){
  const int*   seq   = (const int*)d_in[0];
  const int*   tgt   = (const int*)d_in[1];
  const int*   swnb  = (const int*)d_in[2];
  const float* embw  = (const float*)d_in[3];
  const float* vew   = (const float*)d_in[4];
  const float* qkvw  = (const float*)d_in[5];
  const float* alam  = (const float*)d_in[6];
  const float* aproj = (const float*)d_in[7];
  const float* fcw   = (const float*)d_in[8];
  const float* mproj = (const float*)d_in[9];
  const float* blam  = (const float*)d_in[10];
  const float* skw   = (const float*)d_in[11];
  const float* lmw   = (const float*)d_in[12];

  char* base = (char*)d_ws;
  size_t off = 0;
  auto alloc = [&](size_t bytes){ char* p = base + off; off += (bytes + 255) & ~(size_t)255; return p; };
  float* x     = (float*)alloc((size_t)TT*DD*4);
  float* x0    = (float*)alloc((size_t)TT*DD*4);
  float* skips = (float*)alloc((size_t)5*TT*DD*4);
  float* cosb  = (float*)alloc((size_t)TT*64*4);
  float* sinb  = (float*)alloc((size_t)TT*64*4);
  float* rowsum= (float*)alloc(TT*4);
  float* tl    = (float*)alloc(TT*4);
  int* docs    = (int*)alloc(TT*4);
  int* bmask   = (int*)alloc(4*NBL*NBL*4);
  u16* veg     = (u16*)alloc((size_t)3*TT*DD*2);
  u16* xn_bf   = (u16*)alloc((size_t)TT*DD*2);
  u16* y_bf    = (u16*)alloc((size_t)TT*DD*2);
  u16* hb_bf   = (u16*)alloc((size_t)TT*DFF*2);
  u16* qbf     = (u16*)alloc((size_t)HH*TT*HDIM*2);
  u16* kbf     = (u16*)alloc((size_t)HH*TT*HDIM*2);
  u16* vtb     = (u16*)alloc((size_t)HH*HDIM*TT*2);
  u16* qkvw_bf = (u16*)alloc((size_t)NL*2304*DD*2);
  u16* aprojw_bf = (u16*)alloc((size_t)NL*DD*DD*2);
  u16* fcw_bf  = (u16*)alloc((size_t)NL*DFF*DD*2);
  u16* mprojw_bf = (u16*)alloc((size_t)NL*DD*DFF*2);
  u16* lmw_bf  = (u16*)alloc((size_t)VP*DD*2);

  k_f2bf_all<<<4096, 256, 0, stream>>>(qkvw, aproj, fcw, mproj, lmw,
                                       qkvw_bf, aprojw_bf, fcw_bf, mprojw_bf, lmw_bf);
  k_docs_masks<<<1, 64, 0, stream>>>(seq, swnb, docs, bmask);
  k_embed<<<TT, 256, 0, stream>>>(seq, embw, vew, x, x0, veg, cosb, sinb);

  static const int msel[12] = {0,1,1,1,0,1, 1,0,1,1,1,0};
  for (int i = 0; i < NL; i++){
    // skip-in: layer 6 adds x itself (skips[5] == x at that point); layers 7..11 read saved slots
    const float* sk = nullptr;
    if (i == 6) sk = x;
    else if (i > 6) sk = skips + (size_t)(11 - i)*TT*DD;
    // skip-out: premix(i) saves incoming x as skips[i-1] for i in 1..5
    float* sk_out = (i >= 1 && i <= 5) ? (skips + (size_t)(i - 1)*TT*DD) : nullptr;
    k_premix_norm<<<TT, 256, 0, stream>>>(x, x0, sk, sk_out, skw, i - 6, blam, i, xn_bf);
    if (i != 7){
      const u16* vp = nullptr;
      if (i < 3) vp = veg + (size_t)i*TT*DD;
      else if (i >= 9) vp = veg + (size_t)(i - 9)*TT*DD;
      // qkv GEMM (BN=128): q/k tiles -> rmsnorm+rope -> qbf/kbf; v tiles -> vtb
      k_mfma_gemm<4,128><<<16*18, 256, 0, stream>>>(xn_bf, qkvw_bf + (size_t)i*2304*DD, nullptr,
                                                    nullptr, vp, alam, i, vtb, cosb, sinb, qbf, kbf,
                                                    2304, DD, DD, 18);
      const int* kfm = bmask + (msel[i]*2 + 0)*NBL*NBL;
      const int* kpm = bmask + (msel[i]*2 + 1)*NBL*NBL;
      k_attn_mfma<<<384, 128, 0, stream>>>(qbf, kbf, vtb, y_bf, docs, kfm, kpm);
      // attn proj: BN=64, split-K=2, atomic accumulate into x
      dim3 gap(16*12, 2);
      k_mfma_gemm<5,64><<<gap, 256, 0, stream>>>(y_bf, aprojw_bf + (size_t)i*DD*DD, x,
                                                 nullptr, nullptr, nullptr, 0, nullptr,
                                                 nullptr, nullptr, nullptr, nullptr, DD, 384, DD, 12);
      k_rmsnorm_bf<<<TT, 256, 0, stream>>>(x, xn_bf, nullptr);
    }
    // fc GEMM (BN=64) with fused relu^2 -> bf16
    k_mfma_gemm<3,64><<<16*48, 256, 0, stream>>>(xn_bf, fcw_bf + (size_t)i*DFF*DD, nullptr,
                                                 hb_bf, nullptr, nullptr, 0, nullptr,
                                                 nullptr, nullptr, nullptr, nullptr, DFF, DD, DD, 48);
    // mlp proj: BN=64, split-K=4, atomic accumulate into x
    dim3 gmp(16*12, 4);
    k_mfma_gemm<5,64><<<gmp, 256, 0, stream>>>(hb_bf, mprojw_bf + (size_t)i*DD*DFF, x,
                                               nullptr, nullptr, nullptr, 0, nullptr,
                                               nullptr, nullptr, nullptr, nullptr, DD, 768, DFF, 12);
  }
  k_rmsnorm_bf<<<TT, 256, 0, stream>>>(x, xn_bf, rowsum);
  k_loss_mfma<<<16*(VP/128), 512, 0, stream>>>(xn_bf, lmw_bf, tgt, rowsum, tl);
  k_loss_final<<<1, 256, 0, stream>>>(rowsum, tl, (float*)d_out);
}

// Round 24
// 2150.686 us; speedup vs baseline: 1.0936x; 1.0936x over previous
//
#include <hip/hip_runtime.h>
#include <hip/hip_bf16.h>

#define TT 2048
#define DD 768
#define HH 6
#define HDIM 128
#define NL 12
#define NBL 16
#define BLKSZ 128
#define DFF 3072
#define VP 50304
#define NV 50257
#define EPSF 1.1920929e-07f

typedef unsigned short u16;
typedef __attribute__((ext_vector_type(8))) short short8v;
typedef __attribute__((ext_vector_type(4))) float f32x4;
typedef __attribute__((address_space(3))) void lds_void;
typedef __attribute__((address_space(1))) void gbl_void;

__device__ __forceinline__ u16 f2bf(float f){
  unsigned u = __float_as_uint(f);
  return (u16)((u + 0x7fffu + ((u >> 16) & 1u)) >> 16);
}
__device__ __forceinline__ float bf2f(u16 u){
  return __uint_as_float((unsigned)u << 16);
}
__device__ __forceinline__ void async16(const void* g, void* l){
  __builtin_amdgcn_global_load_lds((const gbl_void*)g, (lds_void*)l, 16, 0, 0);
}

// ---------- reduction helpers ----------
__device__ __forceinline__ float wave_sum(float v){
#pragma unroll
  for (int o = 32; o > 0; o >>= 1) v += __shfl_xor(v, o);
  return v;
}
__device__ __forceinline__ float block_sum(float v){
  __shared__ float sh[9];
  int lane = threadIdx.x & 63, w = threadIdx.x >> 6;
  v = wave_sum(v);
  if (lane == 0) sh[w] = v;
  __syncthreads();
  if (threadIdx.x == 0){
    float tot = 0.f;
    int nw = (blockDim.x + 63) >> 6;
    for (int i = 0; i < nw; i++) tot += sh[i];
    sh[8] = tot;
  }
  __syncthreads();
  return sh[8];
}

// ---------- fp32 -> bf16 bulk convert, all 5 weight tensors in one launch ----------
__global__ void k_f2bf_all(const float* __restrict__ qkvw, const float* __restrict__ aproj,
                           const float* __restrict__ fcw, const float* __restrict__ mproj,
                           const float* __restrict__ lmw,
                           u16* __restrict__ qkvw_bf, u16* __restrict__ aprojw_bf,
                           u16* __restrict__ fcw_bf, u16* __restrict__ mprojw_bf,
                           u16* __restrict__ lmw_bf){
  const long S0 = 2654208;            // qkv groups (12*2304*768/8)
  const long S1 = S0 + 884736;        // + aproj
  const long S2 = S1 + 3538944;       // + fc
  const long S3 = S2 + 3538944;       // + mproj
  const long S4 = S3 + 4829184;       // + lm_head
  long stride = (long)gridDim.x * blockDim.x;
  for (long g = (long)blockIdx.x * blockDim.x + threadIdx.x; g < S4; g += stride){
    const float* in; u16* out; long off;
    if (g < S0){ in = qkvw;  out = qkvw_bf;  off = g; }
    else if (g < S1){ in = aproj; out = aprojw_bf; off = g - S0; }
    else if (g < S2){ in = fcw;   out = fcw_bf;   off = g - S1; }
    else if (g < S3){ in = mproj; out = mprojw_bf; off = g - S2; }
    else { in = lmw; out = lmw_bf; off = g - S3; }
    const float4* p = (const float4*)(in + off * 8);
    float4 a = p[0], b = p[1];
    u16 o[8] = { f2bf(a.x), f2bf(a.y), f2bf(a.z), f2bf(a.w),
                 f2bf(b.x), f2bf(b.y), f2bf(b.z), f2bf(b.w) };
    *(ulonglong2*)(out + off * 8) = *(const ulonglong2*)o;
  }
}

// ---------- docs + block masks (wave-parallel cumsum) ----------
__global__ void k_docs_masks(const int* __restrict__ seq, const int* __restrict__ swnb,
                             int* __restrict__ docs, int* __restrict__ bmask){
  int lane = threadIdx.x;   // 64 threads
  int cnt = 0;
  for (int i = 0; i < 32; i++) cnt += (seq[lane*32 + i] == 50256);
  int incl = cnt;
#pragma unroll
  for (int o = 1; o < 64; o <<= 1){
    int v = __shfl_up(incl, o);
    if (lane >= o) incl += v;
  }
  int run = incl - cnt;
  for (int i = 0; i < 32; i++){
    int t = lane*32 + i;
    run += (seq[t] == 50256);
    docs[t] = run;
  }
  __syncthreads();
  if (lane != 0) return;
  int dlo[NBL], dhi[NBL];
  for (int b = 0; b < NBL; b++){ dlo[b] = docs[b*BLKSZ]; dhi[b] = docs[b*BLKSZ + BLKSZ-1]; }
  int allb[NBL][NBL], partb[NBL][NBL];
  for (int i = 0; i < NBL; i++)
    for (int j = 0; j < NBL; j++){
      int a = (i >= j) && (dlo[i] <= dhi[j]) && (dhi[i] >= dlo[j]);
      int f = (i >  j) && (dlo[i] == dhi[j]) && (dhi[i] == dlo[j]);
      allb[i][j] = f; partb[i][j] = a && !f;
    }
  int sws[2]; sws[0] = swnb[0]; sws[1] = swnb[0] / 2;
  for (int m = 0; m < 2; m++){
    int sw = sws[m];
    for (int i = 0; i < NBL; i++){
      int fullcnt = 0;
      for (int j = 0; j < NBL; j++) fullcnt += allb[i][j];
      int pth = sw - fullcnt; if (pth < 1) pth = 1;
      int pr = 0, fr = 0;
      for (int j = NBL-1; j >= 0; j--){
        int kp = partb[i][j] && (pr < pth);
        int kf = allb[i][j]  && (fr < sw - 1);
        bmask[(m*2+0)*NBL*NBL + i*NBL + j] = kf;
        bmask[(m*2+1)*NBL*NBL + i*NBL + j] = kp;
        pr += partb[i][j]; fr += allb[i][j];
      }
    }
  }
}

// ---------- embedding gather + rmsnorm + ve gathers + rotary tables ----------
__global__ void k_embed(const int* __restrict__ seq, const float* __restrict__ embw,
                        const float* __restrict__ vew, float* __restrict__ x,
                        float* __restrict__ x0, u16* __restrict__ veg,
                        float* __restrict__ cosb, float* __restrict__ sinb){
  int t = blockIdx.x;
  if (threadIdx.x < 64){
    int j = threadIdx.x;
    float c = 1.f, s = 0.f;
    if (j < 32){
      float af = powf(1.0f/1024.0f, (float)j / 31.0f);
      float th = (float)t * af;
      c = cosf(th); s = sinf(th);
    }
    cosb[t*64 + j] = c; sinb[t*64 + j] = s;
  }
  int tok = seq[t];
  const float* row = embw + (size_t)tok * DD;
  float ss = 0.f;
  for (int d = threadIdx.x; d < DD; d += blockDim.x){ float v = row[d]; ss += v*v; }
  float tot = block_sum(ss);
  float rn = rsqrtf(tot / DD + EPSF);
  for (int d = threadIdx.x; d < DD; d += blockDim.x){
    float v = row[d] * rn;
    x[(size_t)t*DD + d] = v; x0[(size_t)t*DD + d] = v;
  }
  for (int j = 0; j < 3; j++){
    const float* vr = vew + ((size_t)j*NV + tok) * DD;
    u16* dst = veg + ((size_t)j*TT + t) * DD;
    for (int d = threadIdx.x; d < DD; d += blockDim.x) dst[d] = f2bf(vr[d]);
  }
}

// ---------- row rmsnorm -> bf16 (optional rowsum zeroing for loss) ----------
__global__ void k_rmsnorm_bf(const float* __restrict__ in, u16* __restrict__ out,
                             float* __restrict__ rowsum){
  int t = blockIdx.x;
  if (rowsum && threadIdx.x == 0) rowsum[t] = 0.f;
  const float* r = in + (size_t)t * DD;
  float ss = 0.f;
  for (int d = threadIdx.x; d < DD; d += blockDim.x){ float v = r[d]; ss += v*v; }
  float tot = block_sum(ss);
  float rn = rsqrtf(tot / DD + EPSF);
  u16* o = out + (size_t)t * DD;
  for (int d = threadIdx.x; d < DD; d += blockDim.x) o[d] = f2bf(r[d] * rn);
}

// ---------- fused: [save incoming x to sk_out]; x = bl0*(x [+ sw*sk]) + bl1*x0; xn = bf16(rmsnorm(x)) ----------
__global__ void k_premix_norm(float* __restrict__ x, const float* __restrict__ x0,
                              const float* __restrict__ sk, float* __restrict__ sk_out,
                              const float* __restrict__ skw, int j,
                              const float* __restrict__ bl, int layer, u16* __restrict__ xn){
  int t = blockIdx.x;
  float bl0 = bl[layer*2], bl1 = bl[layer*2 + 1];
  float sw = sk ? skw[j] : 0.f;
  float vloc[3];
  float ss = 0.f;
  int base = t * DD;
#pragma unroll
  for (int k = 0; k < 3; k++){
    int d = threadIdx.x + k*256;
    float xin = x[base + d];
    if (sk_out) sk_out[base + d] = xin;
    float v = xin;
    if (sk) v += sw * sk[base + d];
    v = bl0 * v + bl1 * x0[base + d];
    vloc[k] = v; ss += v*v;
  }
  float tot = block_sum(ss);
  float rn = rsqrtf(tot / DD + EPSF);
#pragma unroll
  for (int k = 0; k < 3; k++){
    int d = threadIdx.x + k*256;
    x[base + d] = vloc[k];
    xn[base + d] = f2bf(vloc[k] * rn);
  }
}

// ---------- MFMA bf16 GEMM 128xBN tile, XCD-chunked + LDS XOR-swizzle ----------
// MODE 3: Cbf = bf16(relu(acc)^2)
// MODE 4 (BN=128): qkv fused: q/k tiles -> rmsnorm+rope -> bf16 qbf/kbf; v tiles -> vtb
// MODE 5: split-K: C += partial via atomicAdd; blockIdx.y = K-slice, K=slice len, ldk=row stride
// BN=64 uses double-buffered LDS + counted vmcnt prefetch (T3-min schedule).
template<int MODE, int BN>
__global__ __launch_bounds__(256, (BN == 64) ? 3 : 2)
void k_mfma_gemm(const u16* __restrict__ A, const u16* __restrict__ B,
                 float* __restrict__ C, u16* __restrict__ Cbf,
                 const u16* __restrict__ vegp, const float* __restrict__ lam,
                 int layer, u16* __restrict__ vtb,
                 const float* __restrict__ cosb, const float* __restrict__ sinb,
                 u16* __restrict__ qbf, u16* __restrict__ kbf,
                 int N, int K, int ldk, int nbn){
  constexpr int NW   = BN / 32;          // acc cols per wave (2 or 4)
  constexpr int BC   = BN / 32;          // B chunks per wave (2 or 4)
  constexpr int NBUF = (BN == 64) ? 2 : 1;
  __shared__ u16 As[NBUF][128*64];
  __shared__ u16 Bs[NBUF][BN*64];
  __shared__ float qt[(MODE == 4) ? 32*132 : 1];   // q/k epilogue stage (16.9 KB)
  int per = (nbn << 4) >> 3;                 // nwg/8 (requires 16*nbn % 8 == 0)
  int x = (blockIdx.x & 7) * per + (blockIdx.x >> 3);
  int bm = (x & 15) << 7;
  int bn = (x >> 4) * BN;
  int koff = (MODE == 5) ? blockIdx.y * K : 0;
  int tid = threadIdx.x;
  int wid = tid >> 6, lane = tid & 63;
  int wr = wid >> 1, wc = wid & 1;
  int srow = lane >> 3;                      // 0..7 within chunk (== row&7)
  int scol = (((lane & 7) ^ srow) * 8);      // pre-swizzled global col slot
  int l15 = lane & 15, l16 = lane >> 4;
  // precompute staging pointers; bump by 64 elements per stage
  const u16* pa[4];
  const u16* pb[BC];
#pragma unroll
  for (int c = 0; c < 4; c++){
    int row = (wid*4 + c)*8 + srow;
    pa[c] = A + (size_t)(bm + row) * ldk + koff + scol;
  }
#pragma unroll
  for (int c = 0; c < BC; c++){
    int row = (wid*BC + c)*8 + srow;
    pb[c] = B + (size_t)(bn + row) * ldk + koff + scol;
  }
  f32x4 acc[4][NW] = {};
  auto stage = [&](int buf){
#pragma unroll
    for (int c = 0; c < 4; c++){
      async16(pa[c], &As[buf][(wid*4 + c) * 512]);
      pa[c] += 64;
    }
#pragma unroll
    for (int c = 0; c < BC; c++){
      async16(pb[c], &Bs[buf][(wid*BC + c) * 512]);
      pb[c] += 64;
    }
  };
  auto compute = [&](int buf){
#pragma unroll
    for (int kk = 0; kk < 2; kk++){
      short8v a[4], b[NW];
#pragma unroll
      for (int m = 0; m < 4; m++){
        int row = wr*64 + m*16 + l15;
        a[m] = *(const short8v*)(&As[buf][row*64 + ((((kk<<2)|l16) ^ (row&7))<<3)]);
      }
#pragma unroll
      for (int n = 0; n < NW; n++){
        int row = wc*(BN/2) + n*16 + l15;
        b[n] = *(const short8v*)(&Bs[buf][row*64 + ((((kk<<2)|l16) ^ (row&7))<<3)]);
      }
#pragma unroll
      for (int m = 0; m < 4; m++)
#pragma unroll
        for (int n = 0; n < NW; n++)
          acc[m][n] = __builtin_amdgcn_mfma_f32_16x16x32_bf16(a[m], b[n], acc[m][n], 0, 0, 0);
    }
  };
  if constexpr (BN == 64){
    // double-buffered, counted-vmcnt prefetch
    stage(0);
    int KT = K >> 6;
    for (int t = 0; t < KT; t++){
      int cur = t & 1;
      if (t + 1 < KT){
        stage(cur ^ 1);
        asm volatile("s_waitcnt vmcnt(6)" ::: "memory");
      } else {
        asm volatile("s_waitcnt vmcnt(0)" ::: "memory");
      }
      __builtin_amdgcn_s_barrier();
      asm volatile("" ::: "memory");
      compute(cur);
      asm volatile("" ::: "memory");
      __builtin_amdgcn_s_barrier();
    }
  } else {
    for (int k0 = 0; k0 < K; k0 += 64){
      stage(0);
      __syncthreads();
      compute(0);
      __syncthreads();
    }
  }
  if (MODE == 4){
    if (bn >= 1536){
      // v tile: head h = (bn-1536)/128; mix with ve, write transposed vtb[h][d][t]
      int h = (bn - 1536) >> 7;
      float l0 = lam[layer*2], l1 = lam[layer*2 + 1];
#pragma unroll
      for (int m = 0; m < 4; m++){
        int t0 = bm + wr*64 + m*16 + l16*4;
#pragma unroll
        for (int n = 0; n < NW; n++){
          int d = wc*64 + n*16 + l15;
          u16 o[4];
#pragma unroll
          for (int j = 0; j < 4; j++){
            float v = l0 * acc[m][n][j];
            if (vegp) v += l1 * bf2f(vegp[(size_t)(t0 + j)*DD + h*HDIM + d]);
            o[j] = f2bf(v);
          }
          *(ushort4*)(vtb + ((size_t)(h*HDIM + d))*TT + t0) = *(const ushort4*)o;
        }
      }
    } else {
      // q/k tile: 4 passes of 32 rows through LDS, rmsnorm + rope -> bf16
      int h = (bn < 768) ? (bn >> 7) : ((bn - 768) >> 7);
      u16* dstb = (bn < 768) ? qbf : kbf;
#pragma unroll
      for (int p = 0; p < 4; p++){
        if (wr == (p >> 1)){
#pragma unroll
          for (int mm = 0; mm < 2; mm++){
            int m = (p & 1)*2 + mm;
#pragma unroll
            for (int n = 0; n < NW; n++){
              int col = wc*64 + n*16 + l15;
#pragma unroll
              for (int j = 0; j < 4; j++){
                int lr = m*16 + l16*4 + j - (p & 1)*32;
                qt[lr*132 + col] = acc[m][n][j];
              }
            }
          }
        }
        __syncthreads();
        {
          int row = tid >> 3, part = tid & 7;   // 8 threads/row, 16 dims each
          int tok = bm + p*32 + row;
          float ss = 0.f;
#pragma unroll
          for (int jj = 0; jj < 16; jj++){
            float v = qt[row*132 + part*16 + jj];
            ss += v*v;
          }
          ss += __shfl_xor(ss, 1); ss += __shfl_xor(ss, 2); ss += __shfl_xor(ss, 4);
          float rn = rsqrtf(ss / 128.f + EPSF);
          if (part < 4){
            u16* dst = dstb + ((size_t)(h*TT + tok))*HDIM;
#pragma unroll
            for (int jj = 0; jj < 16; jj++){
              int j = part*16 + jj;
              float c = cosb[tok*64 + j], s = sinb[tok*64 + j];
              float v1 = qt[row*132 + j] * rn;
              float v2 = qt[row*132 + j + 64] * rn;
              dst[j]      = f2bf(v1*c + v2*s);
              dst[j + 64] = f2bf(-v1*s + v2*c);
            }
          }
        }
        __syncthreads();
      }
    }
    return;
  }
#pragma unroll
  for (int m = 0; m < 4; m++){
    int row = bm + wr*64 + m*16 + l16*4;
#pragma unroll
    for (int j = 0; j < 4; j++){
      if (MODE == 3){
        u16* cb = Cbf + (size_t)(row + j) * N + bn + wc*(BN/2) + l15;
#pragma unroll
        for (int n = 0; n < NW; n++){
          float v = fmaxf(acc[m][n][j], 0.f);
          cb[n*16] = f2bf(v * v);
        }
      } else if (MODE == 5){
        float* cp = C + (size_t)(row + j) * N + bn + wc*(BN/2) + l15;
#pragma unroll
        for (int n = 0; n < NW; n++) atomicAdd(cp + n*16, acc[m][n][j]);
      } else {
        float* cp = C + (size_t)(row + j) * N + bn + wc*(BN/2) + l15;
#pragma unroll
        for (int n = 0; n < NW; n++) cp[n*16] = acc[m][n][j];
      }
    }
  }
}

// ---------- lm_head loss GEMM: 128x128 tile, 512 threads (2x4 waves), dbuf + counted vmcnt ----------
__global__ __launch_bounds__(512) void k_loss_mfma(const u16* __restrict__ A, const u16* __restrict__ B,
                                                   const int* __restrict__ tgt, float* __restrict__ rowsum,
                                                   float* __restrict__ tl){
  __shared__ u16 As[2][128*64];
  __shared__ u16 Bs[2][128*64];
  const int nbn = VP/128;                    // 393
  int per = (nbn << 4) >> 3;
  int x = (blockIdx.x & 7) * per + (blockIdx.x >> 3);
  int bm = (x & 15) << 7;
  int bn = (x >> 4) << 7;
  int tid = threadIdx.x;
  int wid = tid >> 6, lane = tid & 63;
  int wr = wid >> 2, wn = wid & 3;           // 2 x 4 wave grid; wave tile 64x32
  int srow = lane >> 3;
  int scol = (((lane & 7) ^ srow) * 8);
  int l15 = lane & 15, l16 = lane >> 4;
  const u16* pa[2];
  const u16* pb[2];
#pragma unroll
  for (int c = 0; c < 2; c++){
    int row = (wid*2 + c)*8 + srow;
    pa[c] = A + (size_t)(bm + row) * DD + scol;
    pb[c] = B + (size_t)(bn + row) * DD + scol;
  }
  f32x4 acc[4][2] = {};
  auto stage = [&](int buf){
#pragma unroll
    for (int c = 0; c < 2; c++){
      async16(pa[c], &As[buf][(wid*2 + c) * 512]);
      async16(pb[c], &Bs[buf][(wid*2 + c) * 512]);
      pa[c] += 64; pb[c] += 64;
    }
  };
  auto compute = [&](int buf){
#pragma unroll
    for (int kk = 0; kk < 2; kk++){
      short8v a[4], b[2];
#pragma unroll
      for (int m = 0; m < 4; m++){
        int row = wr*64 + m*16 + l15;
        a[m] = *(const short8v*)(&As[buf][row*64 + ((((kk<<2)|l16) ^ (row&7))<<3)]);
      }
#pragma unroll
      for (int n = 0; n < 2; n++){
        int row = wn*32 + n*16 + l15;
        b[n] = *(const short8v*)(&Bs[buf][row*64 + ((((kk<<2)|l16) ^ (row&7))<<3)]);
      }
#pragma unroll
      for (int m = 0; m < 4; m++)
#pragma unroll
        for (int n = 0; n < 2; n++)
          acc[m][n] = __builtin_amdgcn_mfma_f32_16x16x32_bf16(a[m], b[n], acc[m][n], 0, 0, 0);
    }
  };
  stage(0);
  const int KT = DD >> 6;                    // 12
  for (int t = 0; t < KT; t++){
    int cur = t & 1;
    if (t + 1 < KT){
      stage(cur ^ 1);
      asm volatile("s_waitcnt vmcnt(4)" ::: "memory");
    } else {
      asm volatile("s_waitcnt vmcnt(0)" ::: "memory");
    }
    __builtin_amdgcn_s_barrier();
    asm volatile("" ::: "memory");
    __builtin_amdgcn_s_setprio(1);
    compute(cur);
    __builtin_amdgcn_s_setprio(0);
    asm volatile("" ::: "memory");
    __builtin_amdgcn_s_barrier();
  }
  const float INVS = 0.0048112522432469f; // 1/(7.5*sqrt(768))
#pragma unroll
  for (int m = 0; m < 4; m++){
#pragma unroll
    for (int j = 0; j < 4; j++){
      int row = bm + wr*64 + m*16 + l16*4 + j;
      int tg = tgt[row];
      float rs = 0.f;
#pragma unroll
      for (int n = 0; n < 2; n++){
        int col = bn + wn*32 + n*16 + l15;
        float lg = 30.f * __builtin_amdgcn_rcpf(1.f + __expf(-acc[m][n][j] * INVS));
        rs += __expf(lg);
        if (col == tg) tl[row] = lg;
      }
      rs += __shfl_xor(rs, 1); rs += __shfl_xor(rs, 2);
      rs += __shfl_xor(rs, 4); rs += __shfl_xor(rs, 8);
      if (l15 == 0) atomicAdd(&rowsum[row], rs);
    }
  }
}

// ---------- MFMA flash attention: 1D grid, XCD-chunked, longest-qtile-first ----------
__global__ __launch_bounds__(256) void k_attn_mfma(
    const u16* __restrict__ qbf, const u16* __restrict__ kbf, const u16* __restrict__ vtb,
    u16* __restrict__ y, const int* __restrict__ docs,
    const int* __restrict__ kfm, const int* __restrict__ kpm){
  __shared__ u16 Ks[128*128];   // K block; rows 0..63 reused for P
  __shared__ u16 Vs[128*128];   // V^T block [d][k]
  __shared__ int docsL[128];
  __shared__ int kb[NBL], kfl[NBL];
  __shared__ int nkb_sh;
  // 192 blocks = 8 XCD chunks x 24; head-major within chunk, longest qtile first
  int wg = (blockIdx.x & 7) * 24 + (blockIdx.x >> 3);
  int h = wg >> 5;
  int qb = (31 - (wg & 31)) * 64;
  int bt = qb >> 7;
  int tid = threadIdx.x;
  int w = tid >> 6, lane = tid & 63;
  int l15 = lane & 15, l16 = lane >> 4;
  if (tid == 0){
    int n = 0;
    for (int sb = 0; sb <= bt; sb++){
      int kf = kfm[bt*NBL + sb], kp = kpm[bt*NBL + sb];
      if (kf || kp){ kb[n] = sb; kfl[n] = kf; n++; }
    }
    nkb_sh = n;
  }
  short8v q[4];
  {
    const u16* qrow = qbf + ((size_t)(h*TT + qb + w*16 + l15))*HDIM;
#pragma unroll
    for (int kc = 0; kc < 4; kc++) q[kc] = *(const short8v*)(qrow + kc*32 + l16*8);
  }
  int t_row[4], dq[4];
#pragma unroll
  for (int j = 0; j < 4; j++){
    t_row[j] = qb + w*16 + l16*4 + j;
    dq[j] = docs[t_row[j]];
  }
  f32x4 o[8] = {};
  float m[4], l[4];
#pragma unroll
  for (int j = 0; j < 4; j++){ m[j] = -1e30f; l[j] = 0.f; }
  __syncthreads();
  int nkb = nkb_sh;
  for (int bi = 0; bi < nkb; bi++){
    int kbi = kb[bi], kf = kfl[bi];
    __syncthreads();                      // prev-iter readers done
    {
      const u16* ksrc = kbf + ((size_t)(h*TT + kbi*128))*HDIM;
      const u16* vsrc = vtb + ((size_t)(h*HDIM))*TT + kbi*128;
#pragma unroll
      for (int p = 0; p < 8; p++){
        int idx = tid + p*256;
        int r = idx >> 4, c = (idx & 15) * 8;
        short8v kv = *(const short8v*)(ksrc + (size_t)r*HDIM + c);
        *(short8v*)(Ks + ((r*128 + c) ^ ((r&7)<<3))) = kv;
        short8v vv = *(const short8v*)(vsrc + (size_t)r*TT + c);
        *(short8v*)(Vs + ((r*128 + c) ^ ((r&7)<<3))) = vv;
      }
      if (tid < 32) ((int4*)docsL)[tid] = ((const int4*)(docs + kbi*128))[tid];
    }
    __syncthreads();
    // S = Q K^T
    f32x4 s[8];
#pragma unroll
    for (int n = 0; n < 8; n++){
      f32x4 acc = {};
#pragma unroll
      for (int kc = 0; kc < 4; kc++){
        int row = n*16 + l15;
        short8v b = *(const short8v*)(Ks + ((row*128 + kc*32 + l16*8) ^ ((row&7)<<3)));
        acc = __builtin_amdgcn_mfma_f32_16x16x32_bf16(q[kc], b, acc, 0, 0, 0);
      }
      s[n] = acc;
    }
    int sbase = kbi*128;
    float bmax[4];
#pragma unroll
    for (int j = 0; j < 4; j++) bmax[j] = -1e30f;
#pragma unroll
    for (int n = 0; n < 8; n++){
      int sg = sbase + n*16 + l15;
      int ds = docsL[n*16 + l15];
#pragma unroll
      for (int j = 0; j < 4; j++){
        float sv = s[n][j] * 0.12f;
        bool keep = kf || ((sg <= t_row[j]) && (ds == dq[j]));
        sv = keep ? sv : -1e30f;
        s[n][j] = sv;
        bmax[j] = fmaxf(bmax[j], sv);
      }
    }
#pragma unroll
    for (int j = 0; j < 4; j++){
#pragma unroll
      for (int off = 1; off < 16; off <<= 1) bmax[j] = fmaxf(bmax[j], __shfl_xor(bmax[j], off));
      float nm = fmaxf(m[j], bmax[j]);
      float r = __expf(m[j] - nm);
      m[j] = nm; l[j] *= r;
#pragma unroll
      for (int n = 0; n < 8; n++) o[n][j] *= r;
    }
    __syncthreads();                      // all waves done reading Ks
#pragma unroll
    for (int n = 0; n < 8; n++){
#pragma unroll
      for (int j = 0; j < 4; j++){
        float sv = s[n][j];
        float p = (sv > -1e29f) ? __expf(sv - m[j]) : 0.f;
        l[j] += p;
        int prow = w*16 + l16*4 + j;
        Ks[((prow*128) + n*16 + l15) ^ ((prow&7)<<3)] = f2bf(p);
      }
    }
    __syncthreads();
    short8v a[4];
    {
      int prow = w*16 + l15;
#pragma unroll
      for (int kc = 0; kc < 4; kc++)
        a[kc] = *(const short8v*)(Ks + ((prow*128 + kc*32 + l16*8) ^ ((prow&7)<<3)));
    }
#pragma unroll
    for (int n = 0; n < 8; n++){
#pragma unroll
      for (int kc = 0; kc < 4; kc++){
        int vrow = n*16 + l15;
        short8v b = *(const short8v*)(Vs + ((vrow*128 + kc*32 + l16*8) ^ ((vrow&7)<<3)));
        o[n] = __builtin_amdgcn_mfma_f32_16x16x32_bf16(a[kc], b, o[n], 0, 0, 0);
      }
    }
  }
  float inv[4];
#pragma unroll
  for (int j = 0; j < 4; j++){
    float lt = l[j];
#pragma unroll
    for (int off = 1; off < 16; off <<= 1) lt += __shfl_xor(lt, off);
    inv[j] = 1.f / lt;
  }
#pragma unroll
  for (int n = 0; n < 8; n++){
#pragma unroll
    for (int j = 0; j < 4; j++)
      y[(size_t)t_row[j]*DD + h*HDIM + n*16 + l15] = f2bf(o[n][j] * inv[j]);
  }
}

__global__ void k_loss_final(const float* __restrict__ rowsum, const float* __restrict__ tl,
                             float* __restrict__ out){
  float a = 0.f;
  for (int t = threadIdx.x; t < TT; t += 256) a += logf(rowsum[t]) - tl[t];
  a = block_sum(a);
  if (threadIdx.x == 0) out[0] = a / TT;
}

extern "C" void kernel_launch(void* const* d_in, const int* in_sizes, int n_in,
                              void* d_out, int out_size, void* d_ws, size_t ws_size,
                              hipStream_t stream){
  const int*   seq   = (const int*)d_in[0];
  const int*   tgt   = (const int*)d_in[1];
  const int*   swnb  = (const int*)d_in[2];
  const float* embw  = (const float*)d_in[3];
  const float* vew   = (const float*)d_in[4];
  const float* qkvw  = (const float*)d_in[5];
  const float* alam  = (const float*)d_in[6];
  const float* aproj = (const float*)d_in[7];
  const float* fcw   = (const float*)d_in[8];
  const float* mproj = (const float*)d_in[9];
  const float* blam  = (const float*)d_in[10];
  const float* skw   = (const float*)d_in[11];
  const float* lmw   = (const float*)d_in[12];

  char* base = (char*)d_ws;
  size_t off = 0;
  auto alloc = [&](size_t bytes){ char* p = base + off; off += (bytes + 255) & ~(size_t)255; return p; };
  float* x     = (float*)alloc((size_t)TT*DD*4);
  float* x0    = (float*)alloc((size_t)TT*DD*4);
  float* skips = (float*)alloc((size_t)5*TT*DD*4);
  float* cosb  = (float*)alloc((size_t)TT*64*4);
  float* sinb  = (float*)alloc((size_t)TT*64*4);
  float* rowsum= (float*)alloc(TT*4);
  float* tl    = (float*)alloc(TT*4);
  int* docs    = (int*)alloc(TT*4);
  int* bmask   = (int*)alloc(4*NBL*NBL*4);
  u16* veg     = (u16*)alloc((size_t)3*TT*DD*2);
  u16* xn_bf   = (u16*)alloc((size_t)TT*DD*2);
  u16* y_bf    = (u16*)alloc((size_t)TT*DD*2);
  u16* hb_bf   = (u16*)alloc((size_t)TT*DFF*2);
  u16* qbf     = (u16*)alloc((size_t)HH*TT*HDIM*2);
  u16* kbf     = (u16*)alloc((size_t)HH*TT*HDIM*2);
  u16* vtb     = (u16*)alloc((size_t)HH*HDIM*TT*2);
  u16* qkvw_bf = (u16*)alloc((size_t)NL*2304*DD*2);
  u16* aprojw_bf = (u16*)alloc((size_t)NL*DD*DD*2);
  u16* fcw_bf  = (u16*)alloc((size_t)NL*DFF*DD*2);
  u16* mprojw_bf = (u16*)alloc((size_t)NL*DD*DFF*2);
  u16* lmw_bf  = (u16*)alloc((size_t)VP*DD*2);

  k_f2bf_all<<<4096, 256, 0, stream>>>(qkvw, aproj, fcw, mproj, lmw,
                                       qkvw_bf, aprojw_bf, fcw_bf, mprojw_bf, lmw_bf);
  k_docs_masks<<<1, 64, 0, stream>>>(seq, swnb, docs, bmask);
  k_embed<<<TT, 256, 0, stream>>>(seq, embw, vew, x, x0, veg, cosb, sinb);

  static const int msel[12] = {0,1,1,1,0,1, 1,0,1,1,1,0};
  for (int i = 0; i < NL; i++){
    // skip-in: layer 6 adds x itself (skips[5] == x at that point); layers 7..11 read saved slots
    const float* sk = nullptr;
    if (i == 6) sk = x;
    else if (i > 6) sk = skips + (size_t)(11 - i)*TT*DD;
    // skip-out: premix(i) saves incoming x as skips[i-1] for i in 1..5
    float* sk_out = (i >= 1 && i <= 5) ? (skips + (size_t)(i - 1)*TT*DD) : nullptr;
    k_premix_norm<<<TT, 256, 0, stream>>>(x, x0, sk, sk_out, skw, i - 6, blam, i, xn_bf);
    if (i != 7){
      const u16* vp = nullptr;
      if (i < 3) vp = veg + (size_t)i*TT*DD;
      else if (i >= 9) vp = veg + (size_t)(i - 9)*TT*DD;
      // qkv GEMM (BN=128): q/k tiles -> rmsnorm+rope -> qbf/kbf; v tiles -> vtb
      k_mfma_gemm<4,128><<<16*18, 256, 0, stream>>>(xn_bf, qkvw_bf + (size_t)i*2304*DD, nullptr,
                                                    nullptr, vp, alam, i, vtb, cosb, sinb, qbf, kbf,
                                                    2304, DD, DD, 18);
      const int* kfm = bmask + (msel[i]*2 + 0)*NBL*NBL;
      const int* kpm = bmask + (msel[i]*2 + 1)*NBL*NBL;
      k_attn_mfma<<<192, 256, 0, stream>>>(qbf, kbf, vtb, y_bf, docs, kfm, kpm);
      // attn proj: BN=64, split-K=2, atomic accumulate into x
      dim3 gap(16*12, 2);
      k_mfma_gemm<5,64><<<gap, 256, 0, stream>>>(y_bf, aprojw_bf + (size_t)i*DD*DD, x,
                                                 nullptr, nullptr, nullptr, 0, nullptr,
                                                 nullptr, nullptr, nullptr, nullptr, DD, 384, DD, 12);
      k_rmsnorm_bf<<<TT, 256, 0, stream>>>(x, xn_bf, nullptr);
    }
    // fc GEMM (BN=64) with fused relu^2 -> bf16
    k_mfma_gemm<3,64><<<16*48, 256, 0, stream>>>(xn_bf, fcw_bf + (size_t)i*DFF*DD, nullptr,
                                                 hb_bf, nullptr, nullptr, 0, nullptr,
                                                 nullptr, nullptr, nullptr, nullptr, DFF, DD, DD, 48);
    // mlp proj: BN=64, split-K=4, atomic accumulate into x
    dim3 gmp(16*12, 4);
    k_mfma_gemm<5,64><<<gmp, 256, 0, stream>>>(hb_bf, mprojw_bf + (size_t)i*DD*DFF, x,
                                               nullptr, nullptr, nullptr, 0, nullptr,
                                               nullptr, nullptr, nullptr, nullptr, DD, 768, DFF, 12);
  }
  k_rmsnorm_bf<<<TT, 256, 0, stream>>>(x, xn_bf, rowsum);
  k_loss_mfma<<<16*(VP/128), 512, 0, stream>>>(xn_bf, lmw_bf, tgt, rowsum, tl);
  k_loss_final<<<1, 256, 0, stream>>>(rowsum, tl, (float*)d_out);
}